// Round 9
// baseline (423.626 us; speedup 1.0000x reference)
//
#include <hip/hip_runtime.h>

typedef _Float16 f16;
typedef f16 f16x2 __attribute__((ext_vector_type(2)));
typedef f16 f16x4 __attribute__((ext_vector_type(4)));
typedef f16 f16x8 __attribute__((ext_vector_type(8)));
typedef float f32x4 __attribute__((ext_vector_type(4)));

union v8split { f16x8 v8; f16x2 v2[4]; };

// ---------------- d_ws layout (single-pass split path) ----------------
// wq_h 384KB | wp_h 128KB | xw_all 67.1MB | qkv_all 201.3MB  => 269 MB
// (round-8 counters showed the harness poisons 512 MiB of d_ws, so this fits)
#define WQH_OFF 0
#define WPH_OFF (768 * 256 * 2)                         // 393216
#define XW_OFF  (WPH_OFF + 256 * 256 * 2)               // 524288
#define QKV_OFF_WS (XW_OFF + (size_t)2048 * 16384 * 2)  // +67108864
#define WS_NEED    (QKV_OFF_WS + (size_t)2048 * 49152 * 2)  // 268959744

// fp32 -> fp16 weight conversion (w_qkv 768x256, w_proj 256x256)
__global__ __launch_bounds__(256) void cvt_weights_k(
    const float* __restrict__ wq, const float* __restrict__ wp,
    f16* __restrict__ wq_h, f16* __restrict__ wp_h) {
  int idx = blockIdx.x * 256 + threadIdx.x;
  if (idx < 768 * 256) wq_h[idx] = (f16)wq[idx];
  else wp_h[idx - 768 * 256] = (f16)wp[idx - 768 * 256];
}

// XOR-swizzled addr into a 64x512B LDS tile (out2) — validated rounds 7-8
// paired with the GEMM2 read pattern below.
__device__ __forceinline__ char* xwp(char* s, int row, int colbyte) {
  return s + row * 512 + (colbyte ^ (((row ^ (row >> 3)) & 7) << 4));
}

// swap with the adjacent lane (lane ^ 1) via quad_perm [1,0,3,2]
__device__ __forceinline__ float qswapf(float v) {
  int x = __builtin_bit_cast(int, v);
  x = __builtin_amdgcn_update_dpp(0, x, 0xB1, 0xf, 0xf, true);
  return __builtin_bit_cast(float, x);
}

#if __has_builtin(__builtin_amdgcn_fdot2)
__device__ __forceinline__ float fdot2f(f16x2 a, f16x2 b, float c) {
  return __builtin_amdgcn_fdot2(a, b, c, false);
}
#else
__device__ __forceinline__ float fdot2f(f16x2 a, f16x2 b, float c) {
  return c + (float)a[0] * (float)b[0] + (float)a[1] * (float)b[1];
}
#endif

// ---- K1: gather/transpose x (fp32 strided, full-line reads) -> xw_all
// (fp16, per-window contiguous, LINEAR [64 t][256 c2]).
__global__ __launch_bounds__(256) void gather_k(const float* __restrict__ x,
                                                f16* __restrict__ xw_all) {
  const int g = blockIdx.x >> 4, cb = blockIdx.x & 15;
  const int b = g >> 6, iw = (g >> 3) & 7, jw = g & 7;
  const int tid = threadIdx.x;
  const int c = cb * 16 + (tid >> 4), a = (tid >> 2) & 3, bb = tid & 3;
  const float* src = x + (size_t)b * 8388608 + (size_t)c * 32768 +
                     (iw * 4 + a) * 1024 + (jw * 4 + bb) * 32;
  const int t = c >> 2;
  const int byt = t * 512 + (c & 3) * 128 + a * 32 + bb * 8;  // linear
  char* wbase = (char*)(xw_all + (size_t)(g << 3) * 16384) + byt;
#pragma unroll
  for (int kw = 0; kw < 8; ++kw) {
    float4 v = *(const float4*)(src + kw * 4);
    f16x4 h;
    h[0] = (f16)v.x; h[1] = (f16)v.y; h[2] = (f16)v.z; h[3] = (f16)v.w;
    *(f16x4*)(wbase + kw * 32768) = h;
  }
}

// ---- K2a: qkv[t][f] GEMM, one window per block (2048 blocks). No LDS, no
// barriers; xw window slab (32KB) L1/L2-hot; acc split in 2 halves so peak
// live regs stay < 128 (round-7/8 validated, no spills).
__global__ __launch_bounds__(512) void qkv_gemm_k(
    const f16* __restrict__ xw_all, const f16* __restrict__ wq_h,
    f16* __restrict__ qkvg) {
  const int wi = blockIdx.x;
  const f16* xb = xw_all + (size_t)wi * 16384;
  f16* qb = qkvg + (size_t)wi * 49152;
  const int wv = threadIdx.x >> 6, lane = threadIdx.x & 63;
  const int lcol = lane & 15, lq = lane >> 4;
#pragma unroll 1
  for (int half = 0; half < 2; ++half) {
    f32x4 acc[3][4] = {};
    const int fs = wv * 96 + half * 48;
#pragma unroll
    for (int kt = 0; kt < 8; ++kt) {
      f16x8 bf[4];
#pragma unroll
      for (int nt = 0; nt < 4; ++nt)
        bf[nt] = *(const f16x8*)(xb + (nt * 16 + lcol) * 256 + kt * 32 + lq * 8);
#pragma unroll
      for (int ms = 0; ms < 3; ++ms) {
        f16x8 af = *(const f16x8*)(wq_h + (size_t)(fs + ms * 16 + lcol) * 256 + kt * 32 + lq * 8);
#pragma unroll
        for (int nt = 0; nt < 4; ++nt)
          acc[ms][nt] = __builtin_amdgcn_mfma_f32_16x16x32_f16(af, bf[nt], acc[ms][nt], 0, 0, 0);
      }
    }
    // D: col(lane&15)=token (nt*16+lcol), row(lq*4+r)=feature -> f16x4 store
    // of 4 consecutive features at qkv[t][f]  (validated rounds 4-8).
#pragma unroll
    for (int ms = 0; ms < 3; ++ms)
#pragma unroll
      for (int nt = 0; nt < 4; ++nt) {
        f16x4 hv;
        hv[0] = (f16)acc[ms][nt][0]; hv[1] = (f16)acc[ms][nt][1];
        hv[2] = (f16)acc[ms][nt][2]; hv[3] = (f16)acc[ms][nt][3];
        *(f16x4*)(qb + (size_t)(nt * 16 + lcol) * 768 + fs + ms * 16 + lq * 4) = hv;
      }
  }
}

// ---- K2bc: per-token attention (qkv from global) + GEMM2 + DIRECT fp32
// write to out (round-1-validated strided float4 epilogue). LDS = 32KB.
__global__ __launch_bounds__(512) void attn_out_k(
    const f16* __restrict__ qkvg, const f16* __restrict__ wp_h,
    float* __restrict__ out) {
  __shared__ char smem[32768];
  const int wi = blockIdx.x;
  const int kw = wi & 7, jw = (wi >> 3) & 7, iw = (wi >> 6) & 7, bw = wi >> 9;
  const f16* qw = qkvg + (size_t)wi * 49152;
  const int tid = threadIdx.x, wv = tid >> 6, lane = tid & 63;
  const int lcol = lane & 15, lq = lane >> 4;

  // Attention: wave owns 8 tokens; lane = (tt<<3 | h<<1 | dh). Per lane:
  // Q/K/V 32-d half slices read as coalesced f16x8 from global (L2-hot),
  // S merged across dh via quad_perm, exact clip->softmax, fp32 O accum.
  {
    const int tt = lane >> 3, h = (lane >> 1) & 3, dh = lane & 1;
    const int t = wv * 8 + tt;
    const f16* trow = qw + (size_t)t * 768;
    const int de = dh * 32;  // element offset of this lane's d-half

    f16x2 q2[16];
#pragma unroll
    for (int j = 0; j < 4; ++j) {
      v8split u;
      u.v8 = *(const f16x8*)(trow + h * 64 + de + j * 8);
      q2[j * 4 + 0] = u.v2[0]; q2[j * 4 + 1] = u.v2[1];
      q2[j * 4 + 2] = u.v2[2]; q2[j * 4 + 3] = u.v2[3];
    }
    float s[4];
#pragma unroll
    for (int g = 0; g < 4; ++g) {
      float a = 0.f;
#pragma unroll
      for (int j = 0; j < 4; ++j) {
        v8split u;
        u.v8 = *(const f16x8*)(trow + 256 + g * 64 + de + j * 8);
        a = fdot2f(q2[j * 4 + 0], u.v2[0], a);
        a = fdot2f(q2[j * 4 + 1], u.v2[1], a);
        a = fdot2f(q2[j * 4 + 2], u.v2[2], a);
        a = fdot2f(q2[j * 4 + 3], u.v2[3], a);
      }
      s[g] = a;
    }
#pragma unroll
    for (int g = 0; g < 4; ++g) s[g] += qswapf(s[g]);  // merge dh halves

    float mx = -1e30f;
#pragma unroll
    for (int g = 0; g < 4; ++g) {
      float v = fminf(fmaxf(s[g] * 0.125f, -10.f), 10.f);  // clip BEFORE softmax
      s[g] = v; mx = fmaxf(mx, v);
    }
    float sum = 0.f;
#pragma unroll
    for (int g = 0; g < 4; ++g) { s[g] = __expf(s[g] - mx); sum += s[g]; }
    float inv = 1.f / sum;
#pragma unroll
    for (int g = 0; g < 4; ++g) s[g] *= inv;

    float o[32] = {};
#pragma unroll
    for (int g = 0; g < 4; ++g) {
      float p = s[g];
#pragma unroll
      for (int j = 0; j < 4; ++j) {
        v8split u;
        u.v8 = *(const f16x8*)(trow + 512 + g * 64 + de + j * 8);
#pragma unroll
        for (int i = 0; i < 4; ++i) {
          o[j * 8 + 2 * i]     += p * (float)u.v2[i][0];
          o[j * 8 + 2 * i + 1] += p * (float)u.v2[i][1];
        }
      }
    }
    // out2 row = h*16 + t/4, colbyte = (t&3)*128 + dh*64 + j*16 (validated)
    const int row = h * 16 + (t >> 2);
    const int cb0 = (t & 3) * 128 + dh * 64;
#pragma unroll
    for (int j = 0; j < 4; ++j) {
      f16x8 ov;
      ov[0] = (f16)o[j * 8 + 0]; ov[1] = (f16)o[j * 8 + 1];
      ov[2] = (f16)o[j * 8 + 2]; ov[3] = (f16)o[j * 8 + 3];
      ov[4] = (f16)o[j * 8 + 4]; ov[5] = (f16)o[j * 8 + 5];
      ov[6] = (f16)o[j * 8 + 6]; ov[7] = (f16)o[j * 8 + 7];
      *(f16x8*)xwp(smem, row, cb0 + j * 16) = ov;
    }
  }
  __syncthreads();

  // GEMM2 + direct out write (round-1 epilogue: t2 = mt*16+lq*4+r ->
  // out[b][c3][iw*4+mt][jw*4+lq][kw*4+r], float4 over r).
  {
    f32x4 acc2[4][2] = {};
#pragma unroll
    for (int kt = 0; kt < 8; ++kt) {
      f16x8 afr[4];
#pragma unroll
      for (int mt = 0; mt < 4; ++mt)
        afr[mt] = *(const f16x8*)xwp(smem, mt * 16 + lcol, kt * 64 + lq * 16);
#pragma unroll
      for (int nt = 0; nt < 2; ++nt) {
        f16x8 bfr = *(const f16x8*)(wp_h + (size_t)(wv * 32 + nt * 16 + lcol) * 256 + kt * 32 + lq * 8);
#pragma unroll
        for (int mt = 0; mt < 4; ++mt)
          acc2[mt][nt] = __builtin_amdgcn_mfma_f32_16x16x32_f16(afr[mt], bfr, acc2[mt][nt], 0, 0, 0);
      }
    }
    float* ob = out + (size_t)bw * 8388608 + iw * 4096 + jw * 128 + kw * 4;
#pragma unroll
    for (int mt = 0; mt < 4; ++mt)
#pragma unroll
      for (int nt = 0; nt < 2; ++nt) {
        int c3 = wv * 32 + nt * 16 + lcol;
        float4 v;
        v.x = acc2[mt][nt][0]; v.y = acc2[mt][nt][1];
        v.z = acc2[mt][nt][2]; v.w = acc2[mt][nt][3];
        *(float4*)(ob + (size_t)c3 * 32768 + mt * 1024 + lq * 32) = v;
      }
  }
}

// ================= fallback: round-1 fused kernel (validated, ws-light) =====
#define FB_LDQ 68
#define FB_QKV_OFF 32768
#define FB_SPART_OFF (FB_QKV_OFF + 768 * FB_LDQ * 2)
#define FB_SMEM (FB_SPART_OFF + 32 * 64 * 4)

__device__ __forceinline__ char* fb_xwp(char* s, int row, int colbyte) {
  return s + row * 512 + (colbyte ^ ((row & 7) << 4));
}

__global__ __launch_bounds__(512) void fused_fb_k(
    const float* __restrict__ x, const f16* __restrict__ wq_h,
    const f16* __restrict__ wp_h, float* __restrict__ out) {
  extern __shared__ char smem[];
  f16* qkvT = (f16*)(smem + FB_QKV_OFF);
  float* spart = (float*)(smem + FB_SPART_OFF);
  const int tid = threadIdx.x;
  const int wi = blockIdx.x;
  const int kw = wi & 7, jw = (wi >> 3) & 7, iw = (wi >> 6) & 7, bw = wi >> 9;
  const float* xb = x + (size_t)bw * 8388608 + iw * 4096 + jw * 128 + kw * 4;
#pragma unroll
  for (int it = 0; it < 8; ++it) {
    int idx = it * 512 + tid;
    int c = idx >> 4, a = (idx >> 2) & 3, bb = idx & 3;
    float4 v = *(const float4*)(xb + (size_t)c * 32768 + a * 1024 + bb * 32);
    f16x4 h;
    h[0] = (f16)v.x; h[1] = (f16)v.y; h[2] = (f16)v.z; h[3] = (f16)v.w;
    *(f16x4*)fb_xwp(smem, c >> 2, (c & 3) * 128 + a * 32 + bb * 8) = h;
  }
  __syncthreads();
  const int wv = tid >> 6, lane = tid & 63;
  const int lcol = lane & 15, lq = lane >> 4;
  for (int nc = 0; nc < 2; ++nc) {
    const int ncb = wv * 96 + nc * 48;
    f32x4 acc[4][3] = {};
    for (int kt = 0; kt < 8; ++kt) {
      f16x8 afr[4];
#pragma unroll
      for (int mt = 0; mt < 4; ++mt)
        afr[mt] = *(const f16x8*)fb_xwp(smem, mt * 16 + lcol, kt * 64 + lq * 16);
#pragma unroll
      for (int nt = 0; nt < 3; ++nt) {
        f16x8 bfr = *(const f16x8*)(wq_h + (ncb + nt * 16 + lcol) * 256 + kt * 32 + lq * 8);
#pragma unroll
        for (int mt = 0; mt < 4; ++mt)
          acc[mt][nt] = __builtin_amdgcn_mfma_f32_16x16x32_f16(afr[mt], bfr, acc[mt][nt], 0, 0, 0);
      }
    }
#pragma unroll
    for (int mt = 0; mt < 4; ++mt)
#pragma unroll
      for (int nt = 0; nt < 3; ++nt) {
        f16x4 hv;
        hv[0] = (f16)acc[mt][nt][0]; hv[1] = (f16)acc[mt][nt][1];
        hv[2] = (f16)acc[mt][nt][2]; hv[3] = (f16)acc[mt][nt][3];
        *(f16x4*)(qkvT + (ncb + nt * 16 + lcol) * FB_LDQ + mt * 16 + lq * 4) = hv;
      }
  }
  __syncthreads();
  {
    const int h = wv & 3, dh = wv >> 2, t = lane;
    float qreg[32];
#pragma unroll
    for (int dd = 0; dd < 32; ++dd)
      qreg[dd] = (float)qkvT[(h * 64 + dh * 32 + dd) * FB_LDQ + t];
#pragma unroll
    for (int g = 0; g < 4; ++g) {
      float s = 0.f;
#pragma unroll
      for (int dd = 0; dd < 32; ++dd)
        s += qreg[dd] * (float)qkvT[(256 + g * 64 + dh * 32 + dd) * FB_LDQ + t];
      spart[((dh * 4 + h) * 4 + g) * 64 + t] = s;
    }
  }
  __syncthreads();
  {
    const int h = wv & 3, dh = wv >> 2, t = lane;
    float P[4];
    float mx = -1e30f;
#pragma unroll
    for (int g = 0; g < 4; ++g) {
      float s = spart[(h * 4 + g) * 64 + t] + spart[((4 + h) * 4 + g) * 64 + t];
      s *= 0.125f;
      s = fminf(fmaxf(s, -10.f), 10.f);
      P[g] = s;
      mx = fmaxf(mx, s);
    }
    float sum = 0.f;
#pragma unroll
    for (int g = 0; g < 4; ++g) { P[g] = __expf(P[g] - mx); sum += P[g]; }
    float inv = 1.f / sum;
#pragma unroll
    for (int g = 0; g < 4; ++g) P[g] *= inv;
    const int row = h * 16 + (t >> 2);
    const int cb0 = (t & 3) * 128 + dh * 64;
#pragma unroll
    for (int db = 0; db < 32; db += 8) {
      f16x8 hv;
#pragma unroll
      for (int u = 0; u < 8; ++u) {
        int d = dh * 32 + db + u;
        float o = 0.f;
#pragma unroll
        for (int g = 0; g < 4; ++g)
          o += P[g] * (float)qkvT[(512 + g * 64 + d) * FB_LDQ + t];
        hv[u] = (f16)o;
      }
      *(f16x8*)fb_xwp(smem, row, cb0 + db * 2) = hv;
    }
  }
  __syncthreads();
  {
    f32x4 acc[4][2] = {};
    for (int kt = 0; kt < 8; ++kt) {
      f16x8 afr[4];
#pragma unroll
      for (int mt = 0; mt < 4; ++mt)
        afr[mt] = *(const f16x8*)fb_xwp(smem, mt * 16 + lcol, kt * 64 + lq * 16);
#pragma unroll
      for (int nt = 0; nt < 2; ++nt) {
        f16x8 bfr = *(const f16x8*)(wp_h + (wv * 32 + nt * 16 + lcol) * 256 + kt * 32 + lq * 8);
#pragma unroll
        for (int mt = 0; mt < 4; ++mt)
          acc[mt][nt] = __builtin_amdgcn_mfma_f32_16x16x32_f16(afr[mt], bfr, acc[mt][nt], 0, 0, 0);
      }
    }
    float* ob = out + (size_t)bw * 8388608 + iw * 4096 + jw * 128 + kw * 4;
#pragma unroll
    for (int mt = 0; mt < 4; ++mt) {
#pragma unroll
      for (int nt = 0; nt < 2; ++nt) {
        int c3 = wv * 32 + nt * 16 + lcol;
        float4 v;
        v.x = acc[mt][nt][0]; v.y = acc[mt][nt][1];
        v.z = acc[mt][nt][2]; v.w = acc[mt][nt][3];
        *(float4*)(ob + (size_t)c3 * 32768 + mt * 1024 + lq * 32) = v;
      }
    }
  }
}

extern "C" void kernel_launch(void* const* d_in, const int* in_sizes, int n_in,
                              void* d_out, int out_size, void* d_ws, size_t ws_size,
                              hipStream_t stream) {
  const float* x = (const float*)d_in[0];
  const float* wq = (const float*)d_in[1];
  const float* wp = (const float*)d_in[2];
  float* out = (float*)d_out;
  char* ws = (char*)d_ws;
  f16* wq_h = (f16*)(ws + WQH_OFF);
  f16* wp_h = (f16*)(ws + WPH_OFF);

  cvt_weights_k<<<1024, 256, 0, stream>>>(wq, wp, wq_h, wp_h);

  if (ws_size >= WS_NEED) {
    f16* xw_all = (f16*)(ws + XW_OFF);
    f16* qkvg = (f16*)(ws + QKV_OFF_WS);
    gather_k<<<4096, 256, 0, stream>>>(x, xw_all);
    qkv_gemm_k<<<2048, 512, 0, stream>>>(xw_all, wq_h, qkvg);
    attn_out_k<<<2048, 512, 0, stream>>>(qkvg, wp_h, out);
  } else {
    (void)hipFuncSetAttribute((const void*)fused_fb_k,
                              hipFuncAttributeMaxDynamicSharedMemorySize, FB_SMEM);
    fused_fb_k<<<2048, 512, FB_SMEM, stream>>>(x, wq_h, wp_h, out);
  }
}

// Round 10
// 268.640 us; speedup vs baseline: 1.5769x; 1.5769x over previous
//
#include <hip/hip_runtime.h>

typedef _Float16 f16;
typedef f16 f16x2 __attribute__((ext_vector_type(2)));
typedef f16 f16x4 __attribute__((ext_vector_type(4)));
typedef f16 f16x8 __attribute__((ext_vector_type(8)));
typedef float f32x4 __attribute__((ext_vector_type(4)));

union v8split { f16x8 v8; f16x2 v2[4]; };

// ---------------- d_ws layout ----------------
#define WQH_OFF 0
#define WPH_OFF (768 * 256 * 2)                         // 393216
#define XW_OFF  (WPH_OFF + 256 * 256 * 2)               // 524288
#define O2_OFF  (XW_OFF + (size_t)2048 * 16384 * 2)     // +67108864
#define WS_NEED (O2_OFF + (size_t)2048 * 16384 * 2)     // 134742016

// LDS: bufX (xw/out2) 32KB | qkv [64t][768f] 96KB = 128KB -> 1 block/CU
#define QKV_LDS_OFF 32768
#define SMEM_TOTAL 131072

// fp32 -> fp16 weight conversion
__global__ __launch_bounds__(256) void cvt_weights_k(
    const float* __restrict__ wq, const float* __restrict__ wp,
    f16* __restrict__ wq_h, f16* __restrict__ wp_h) {
  int idx = blockIdx.x * 256 + threadIdx.x;
  if (idx < 768 * 256) wq_h[idx] = (f16)wq[idx];
  else wp_h[idx - 768 * 256] = (f16)wp[idx - 768 * 256];
}

// XOR-swizzled addr into a 64x512B tile (xw / out2) — r5-r7 validated pair
// with gather_k's pre-swizzle and the GEMM fragment reads.
__device__ __forceinline__ char* xwp(char* s, int row, int colbyte) {
  return s + row * 512 + (colbyte ^ (((row ^ (row >> 3)) & 7) << 4));
}
// qkv tile [64 t][768 f], row stride 1536B — r4-r7 validated.
__device__ __forceinline__ char* qvp(char* s, int t, int fbyte) {
  return s + QKV_LDS_OFF + t * 1536 + (fbyte ^ ((t & 7) << 4));
}

// swap with lane^1 via quad_perm
__device__ __forceinline__ float qswapf(float v) {
  int x = __builtin_bit_cast(int, v);
  x = __builtin_amdgcn_update_dpp(0, x, 0xB1, 0xf, 0xf, true);
  return __builtin_bit_cast(float, x);
}

#if __has_builtin(__builtin_amdgcn_fdot2)
__device__ __forceinline__ float fdot2f(f16x2 a, f16x2 b, float c) {
  return __builtin_amdgcn_fdot2(a, b, c, false);
}
#else
__device__ __forceinline__ float fdot2f(f16x2 a, f16x2 b, float c) {
  return c + (float)a[0] * (float)b[0] + (float)a[1] * (float)b[1];
}
#endif

// ---- K1: gather/transpose x (fp32 strided, full 128B-line reads) -> xw_all
// (fp16, per-window contiguous, PRE-SWIZZLED to match xwp). r5-r7 validated.
__global__ __launch_bounds__(256) void gather_k(const float* __restrict__ x,
                                                f16* __restrict__ xw_all) {
  const int g = blockIdx.x >> 4, cb = blockIdx.x & 15;
  const int b = g >> 6, iw = (g >> 3) & 7, jw = g & 7;
  const int tid = threadIdx.x;
  const int c = cb * 16 + (tid >> 4), a = (tid >> 2) & 3, bb = tid & 3;
  const float* src = x + (size_t)b * 8388608 + (size_t)c * 32768 +
                     (iw * 4 + a) * 1024 + (jw * 4 + bb) * 32;
  const int t = c >> 2;
  const int c2b = (c & 3) * 128 + a * 32 + bb * 8;
  const int byt = t * 512 + (c2b ^ (((t ^ (t >> 3)) & 7) << 4));
  char* wbase = (char*)(xw_all + (size_t)(g << 3) * 16384) + byt;
#pragma unroll
  for (int kw = 0; kw < 8; ++kw) {
    float4 v = *(const float4*)(src + kw * 4);
    f16x4 h;
    h[0] = (f16)v.x; h[1] = (f16)v.y; h[2] = (f16)v.z; h[3] = (f16)v.w;
    *(f16x4*)(wbase + kw * 32768) = h;
  }
}

// ---- K2: fused per-window kernel, one window per block (no persistent loop,
// the r9-proven spill-free shape). xw->LDS, GEMM1 (acc split), attention from
// LDS, GEMM2 -> o2T.
__global__ __launch_bounds__(512) void win_attn_k(
    const f16* __restrict__ xw_all, const f16* __restrict__ wq_h,
    const f16* __restrict__ wp_h, f16* __restrict__ o2T) {
  extern __shared__ char smem[];
  const int wi = blockIdx.x;
  const int tid = threadIdx.x, wv = tid >> 6, lane = tid & 63;
  const int lcol = lane & 15, lq = lane >> 4;

  // Phase 1: 32KB pre-swizzled xw -> LDS (linear dest + pre-swizzled source).
  {
    const char* g = (const char*)(xw_all + (size_t)wi * 16384) + wv * 4096 + lane * 16;
#pragma unroll
    for (int i = 0; i < 4; ++i)
      __builtin_amdgcn_global_load_lds(
          (const __attribute__((address_space(1))) void*)(g + i * 1024),
          (__attribute__((address_space(3))) void*)(smem + wv * 4096 + i * 1024), 16, 0, 0);
  }
  __syncthreads();

  // Phase 2: GEMM1 qkv[64t x 768f] = (W @ xw^T)^T, wave = 96 f-cols, acc
  // split in 2 halves of [3][4] (48 acc VGPRs) — r7-validated, spill-free.
#pragma unroll 1
  for (int half = 0; half < 2; ++half) {
    f32x4 acc[3][4] = {};
    const int fs = wv * 96 + half * 48;
#pragma unroll
    for (int kt = 0; kt < 8; ++kt) {
      f16x8 bf[4];
#pragma unroll
      for (int nt = 0; nt < 4; ++nt)
        bf[nt] = *(const f16x8*)xwp(smem, nt * 16 + lcol, kt * 64 + lq * 16);
#pragma unroll
      for (int ms = 0; ms < 3; ++ms) {
        f16x8 af = *(const f16x8*)(wq_h + (size_t)(fs + ms * 16 + lcol) * 256 + kt * 32 + lq * 8);
#pragma unroll
        for (int nt = 0; nt < 4; ++nt)
          acc[ms][nt] = __builtin_amdgcn_mfma_f32_16x16x32_f16(af, bf[nt], acc[ms][nt], 0, 0, 0);
      }
    }
    // D: col(lane&15)=token, row(lq*4+r)=feature -> f16x4 to qkv[t][f].
#pragma unroll
    for (int ms = 0; ms < 3; ++ms)
#pragma unroll
      for (int nt = 0; nt < 4; ++nt) {
        f16x4 hv;
        hv[0] = (f16)acc[ms][nt][0]; hv[1] = (f16)acc[ms][nt][1];
        hv[2] = (f16)acc[ms][nt][2]; hv[3] = (f16)acc[ms][nt][3];
        *(f16x4*)qvp(smem, nt * 16 + lcol, (fs + ms * 16 + lq * 4) * 2) = hv;
      }
  }
  __syncthreads();

  // Phase 3: attention. wave owns 8 tokens; lane = (tt<<3 | h<<1 | dh).
  // Q/K/V b128 reads from LDS (broadcast-friendly), dh-halves merged via
  // quad_perm, exact clip->softmax, fp32 O accum. r5-r7 validated.
  {
    const int tt = lane >> 3, h = (lane >> 1) & 3, dh = lane & 1;
    const int t = wv * 8 + tt;
    const int db = dh * 64;  // byte offset of this lane's 32-half d-slice

    f16x2 q2[16];
#pragma unroll
    for (int j = 0; j < 4; ++j) {
      v8split u;
      u.v8 = *(const f16x8*)qvp(smem, t, h * 128 + db + j * 16);
      q2[j * 4 + 0] = u.v2[0]; q2[j * 4 + 1] = u.v2[1];
      q2[j * 4 + 2] = u.v2[2]; q2[j * 4 + 3] = u.v2[3];
    }
    float s[4];
#pragma unroll
    for (int g = 0; g < 4; ++g) {
      float a = 0.f;
#pragma unroll
      for (int j = 0; j < 4; ++j) {
        v8split u;
        u.v8 = *(const f16x8*)qvp(smem, t, 512 + g * 128 + db + j * 16);
        a = fdot2f(q2[j * 4 + 0], u.v2[0], a);
        a = fdot2f(q2[j * 4 + 1], u.v2[1], a);
        a = fdot2f(q2[j * 4 + 2], u.v2[2], a);
        a = fdot2f(q2[j * 4 + 3], u.v2[3], a);
      }
      s[g] = a;
    }
#pragma unroll
    for (int g = 0; g < 4; ++g) s[g] += qswapf(s[g]);  // merge dh halves

    float mx = -1e30f;
#pragma unroll
    for (int g = 0; g < 4; ++g) {
      float v = fminf(fmaxf(s[g] * 0.125f, -10.f), 10.f);  // clip BEFORE softmax
      s[g] = v; mx = fmaxf(mx, v);
    }
    float sum = 0.f;
#pragma unroll
    for (int g = 0; g < 4; ++g) { s[g] = __expf(s[g] - mx); sum += s[g]; }
    float inv = 1.f / sum;
#pragma unroll
    for (int g = 0; g < 4; ++g) s[g] *= inv;

    float o[32] = {};
#pragma unroll
    for (int g = 0; g < 4; ++g) {
      float p = s[g];
#pragma unroll
      for (int j = 0; j < 4; ++j) {
        v8split u;
        u.v8 = *(const f16x8*)qvp(smem, t, 1024 + g * 128 + db + j * 16);
#pragma unroll
        for (int i = 0; i < 4; ++i) {
          o[j * 8 + 2 * i]     += p * (float)u.v2[i][0];
          o[j * 8 + 2 * i + 1] += p * (float)u.v2[i][1];
        }
      }
    }
    // out2 row = h*16 + t/4, colbyte = (t&3)*128 + dh*64 + j*16; reuse bufX.
    const int row = h * 16 + (t >> 2);
    const int cb0 = (t & 3) * 128 + db;
#pragma unroll
    for (int j = 0; j < 4; ++j) {
      f16x8 ov;
      ov[0] = (f16)o[j * 8 + 0]; ov[1] = (f16)o[j * 8 + 1];
      ov[2] = (f16)o[j * 8 + 2]; ov[3] = (f16)o[j * 8 + 3];
      ov[4] = (f16)o[j * 8 + 4]; ov[5] = (f16)o[j * 8 + 5];
      ov[6] = (f16)o[j * 8 + 6]; ov[7] = (f16)o[j * 8 + 7];
      *(f16x8*)xwp(smem, row, cb0 + j * 16) = ov;
    }
  }
  __syncthreads();

  // Phase 4: GEMM2 final[64x256] = out2 @ w_proj^T; D col=c3 -> o2T[c3][t].
  {
    f32x4 acc2[4][2] = {};
#pragma unroll
    for (int kt = 0; kt < 8; ++kt) {
      f16x8 afr[4];
#pragma unroll
      for (int mt = 0; mt < 4; ++mt)
        afr[mt] = *(const f16x8*)xwp(smem, mt * 16 + lcol, kt * 64 + lq * 16);
#pragma unroll
      for (int nt = 0; nt < 2; ++nt) {
        f16x8 bfr = *(const f16x8*)(wp_h + (size_t)(wv * 32 + nt * 16 + lcol) * 256 + kt * 32 + lq * 8);
#pragma unroll
        for (int mt = 0; mt < 4; ++mt)
          acc2[mt][nt] = __builtin_amdgcn_mfma_f32_16x16x32_f16(afr[mt], bfr, acc2[mt][nt], 0, 0, 0);
      }
    }
    f16* ob = o2T + (size_t)wi * 16384;
#pragma unroll
    for (int mt = 0; mt < 4; ++mt)
#pragma unroll
      for (int nt = 0; nt < 2; ++nt) {
        int c3 = wv * 32 + nt * 16 + lcol;
        f16x4 hv;
        hv[0] = (f16)acc2[mt][nt][0]; hv[1] = (f16)acc2[mt][nt][1];
        hv[2] = (f16)acc2[mt][nt][2]; hv[3] = (f16)acc2[mt][nt][3];
        *(f16x4*)(ob + c3 * 64 + mt * 16 + lq * 4) = hv;
      }
  }
}

// ---- K3: scatter o2T (fp16, L3-hot) -> out (fp32, full 128B-line writes).
__global__ __launch_bounds__(256) void scatter_k(const f16* __restrict__ o2T,
                                                 float* __restrict__ out) {
  const int g = blockIdx.x >> 4, cb = blockIdx.x & 15;
  const int b = g >> 6, iw = (g >> 3) & 7, jw = g & 7;
  const int tid = threadIdx.x;
  const int c3 = cb * 16 + (tid >> 4), a = (tid >> 2) & 3, bb = tid & 3;
  const f16* rbase = o2T + (size_t)(g << 3) * 16384 + c3 * 64 + a * 16 + bb * 4;
  float* dst = out + (size_t)b * 8388608 + (size_t)c3 * 32768 +
               (iw * 4 + a) * 1024 + (jw * 4 + bb) * 32;
#pragma unroll
  for (int kw = 0; kw < 8; ++kw) {
    f16x4 h = *(const f16x4*)(rbase + kw * 16384);
    float4 v;
    v.x = (float)h[0]; v.y = (float)h[1]; v.z = (float)h[2]; v.w = (float)h[3];
    *(float4*)(dst + kw * 4) = v;
  }
}

// ================= fallback: round-1 fused kernel (validated, ws-light) =====
#define FB_LDQ 68
#define FB_QKV_OFF 32768
#define FB_SPART_OFF (FB_QKV_OFF + 768 * FB_LDQ * 2)
#define FB_SMEM (FB_SPART_OFF + 32 * 64 * 4)

__device__ __forceinline__ char* fb_xwp(char* s, int row, int colbyte) {
  return s + row * 512 + (colbyte ^ ((row & 7) << 4));
}

__global__ __launch_bounds__(512) void fused_fb_k(
    const float* __restrict__ x, const f16* __restrict__ wq_h,
    const f16* __restrict__ wp_h, float* __restrict__ out) {
  extern __shared__ char smem[];
  f16* qkvT = (f16*)(smem + FB_QKV_OFF);
  float* spart = (float*)(smem + FB_SPART_OFF);
  const int tid = threadIdx.x;
  const int wi = blockIdx.x;
  const int kw = wi & 7, jw = (wi >> 3) & 7, iw = (wi >> 6) & 7, bw = wi >> 9;
  const float* xb = x + (size_t)bw * 8388608 + iw * 4096 + jw * 128 + kw * 4;
#pragma unroll
  for (int it = 0; it < 8; ++it) {
    int idx = it * 512 + tid;
    int c = idx >> 4, a = (idx >> 2) & 3, bb = idx & 3;
    float4 v = *(const float4*)(xb + (size_t)c * 32768 + a * 1024 + bb * 32);
    f16x4 h;
    h[0] = (f16)v.x; h[1] = (f16)v.y; h[2] = (f16)v.z; h[3] = (f16)v.w;
    *(f16x4*)fb_xwp(smem, c >> 2, (c & 3) * 128 + a * 32 + bb * 8) = h;
  }
  __syncthreads();
  const int wv = tid >> 6, lane = tid & 63;
  const int lcol = lane & 15, lq = lane >> 4;
  for (int nc = 0; nc < 2; ++nc) {
    const int ncb = wv * 96 + nc * 48;
    f32x4 acc[4][3] = {};
    for (int kt = 0; kt < 8; ++kt) {
      f16x8 afr[4];
#pragma unroll
      for (int mt = 0; mt < 4; ++mt)
        afr[mt] = *(const f16x8*)fb_xwp(smem, mt * 16 + lcol, kt * 64 + lq * 16);
#pragma unroll
      for (int nt = 0; nt < 3; ++nt) {
        f16x8 bfr = *(const f16x8*)(wq_h + (ncb + nt * 16 + lcol) * 256 + kt * 32 + lq * 8);
#pragma unroll
        for (int mt = 0; mt < 4; ++mt)
          acc[mt][nt] = __builtin_amdgcn_mfma_f32_16x16x32_f16(afr[mt], bfr, acc[mt][nt], 0, 0, 0);
      }
    }
#pragma unroll
    for (int mt = 0; mt < 4; ++mt)
#pragma unroll
      for (int nt = 0; nt < 3; ++nt) {
        f16x4 hv;
        hv[0] = (f16)acc[mt][nt][0]; hv[1] = (f16)acc[mt][nt][1];
        hv[2] = (f16)acc[mt][nt][2]; hv[3] = (f16)acc[mt][nt][3];
        *(f16x4*)(qkvT + (ncb + nt * 16 + lcol) * FB_LDQ + mt * 16 + lq * 4) = hv;
      }
  }
  __syncthreads();
  {
    const int h = wv & 3, dh = wv >> 2, t = lane;
    float qreg[32];
#pragma unroll
    for (int dd = 0; dd < 32; ++dd)
      qreg[dd] = (float)qkvT[(h * 64 + dh * 32 + dd) * FB_LDQ + t];
#pragma unroll
    for (int g = 0; g < 4; ++g) {
      float s = 0.f;
#pragma unroll
      for (int dd = 0; dd < 32; ++dd)
        s += qreg[dd] * (float)qkvT[(256 + g * 64 + dh * 32 + dd) * FB_LDQ + t];
      spart[((dh * 4 + h) * 4 + g) * 64 + t] = s;
    }
  }
  __syncthreads();
  {
    const int h = wv & 3, dh = wv >> 2, t = lane;
    float P[4];
    float mx = -1e30f;
#pragma unroll
    for (int g = 0; g < 4; ++g) {
      float s = spart[(h * 4 + g) * 64 + t] + spart[((4 + h) * 4 + g) * 64 + t];
      s *= 0.125f;
      s = fminf(fmaxf(s, -10.f), 10.f);
      P[g] = s;
      mx = fmaxf(mx, s);
    }
    float sum = 0.f;
#pragma unroll
    for (int g = 0; g < 4; ++g) { P[g] = __expf(P[g] - mx); sum += P[g]; }
    float inv = 1.f / sum;
#pragma unroll
    for (int g = 0; g < 4; ++g) P[g] *= inv;
    const int row = h * 16 + (t >> 2);
    const int cb0 = (t & 3) * 128 + dh * 64;
#pragma unroll
    for (int db = 0; db < 32; db += 8) {
      f16x8 hv;
#pragma unroll
      for (int u = 0; u < 8; ++u) {
        int d = dh * 32 + db + u;
        float o = 0.f;
#pragma unroll
        for (int g = 0; g < 4; ++g)
          o += P[g] * (float)qkvT[(512 + g * 64 + d) * FB_LDQ + t];
        hv[u] = (f16)o;
      }
      *(f16x8*)fb_xwp(smem, row, cb0 + db * 2) = hv;
    }
  }
  __syncthreads();
  {
    f32x4 acc[4][2] = {};
    for (int kt = 0; kt < 8; ++kt) {
      f16x8 afr[4];
#pragma unroll
      for (int mt = 0; mt < 4; ++mt)
        afr[mt] = *(const f16x8*)fb_xwp(smem, mt * 16 + lcol, kt * 64 + lq * 16);
#pragma unroll
      for (int nt = 0; nt < 2; ++nt) {
        f16x8 bfr = *(const f16x8*)(wp_h + (wv * 32 + nt * 16 + lcol) * 256 + kt * 32 + lq * 8);
#pragma unroll
        for (int mt = 0; mt < 4; ++mt)
          acc[mt][nt] = __builtin_amdgcn_mfma_f32_16x16x32_f16(afr[mt], bfr, acc[mt][nt], 0, 0, 0);
      }
    }
    float* ob = out + (size_t)bw * 8388608 + iw * 4096 + jw * 128 + kw * 4;
#pragma unroll
    for (int mt = 0; mt < 4; ++mt) {
#pragma unroll
      for (int nt = 0; nt < 2; ++nt) {
        int c3 = wv * 32 + nt * 16 + lcol;
        float4 v;
        v.x = acc[mt][nt][0]; v.y = acc[mt][nt][1];
        v.z = acc[mt][nt][2]; v.w = acc[mt][nt][3];
        *(float4*)(ob + (size_t)c3 * 32768 + mt * 1024 + lq * 32) = v;
      }
    }
  }
}

extern "C" void kernel_launch(void* const* d_in, const int* in_sizes, int n_in,
                              void* d_out, int out_size, void* d_ws, size_t ws_size,
                              hipStream_t stream) {
  const float* x = (const float*)d_in[0];
  const float* wq = (const float*)d_in[1];
  const float* wp = (const float*)d_in[2];
  float* out = (float*)d_out;
  char* ws = (char*)d_ws;
  f16* wq_h = (f16*)(ws + WQH_OFF);
  f16* wp_h = (f16*)(ws + WPH_OFF);

  cvt_weights_k<<<1024, 256, 0, stream>>>(wq, wp, wq_h, wp_h);

  if (ws_size >= WS_NEED) {
    f16* xw_all = (f16*)(ws + XW_OFF);
    f16* o2T = (f16*)(ws + O2_OFF);
    (void)hipFuncSetAttribute((const void*)win_attn_k,
                              hipFuncAttributeMaxDynamicSharedMemorySize, SMEM_TOTAL);
    gather_k<<<4096, 256, 0, stream>>>(x, xw_all);
    win_attn_k<<<2048, 512, SMEM_TOTAL, stream>>>(xw_all, wq_h, wp_h, o2T);
    scatter_k<<<4096, 256, 0, stream>>>(o2T, out);
  } else {
    (void)hipFuncSetAttribute((const void*)fused_fb_k,
                              hipFuncAttributeMaxDynamicSharedMemorySize, FB_SMEM);
    fused_fb_k<<<2048, 512, FB_SMEM, stream>>>(x, wq_h, wp_h, out);
  }
}